// Round 1
// baseline (161.341 us; speedup 1.0000x reference)
//
#include <hip/hip_runtime.h>

// LinearAttention: out[b,n,v] = sum_k q[b,k,n] * ktv[b,k,v],
//                  ktv[b,k,v] = sum_n K[b,n,k] * V[b,n,v]
// B=16, DK=64, N=8192, DV=64, fp32.

#define B_   16
#define N_   8192
#define DK_  64
#define DV_  64

// ---------------- Phase 1: partial K^T V per (chunk, batch) ----------------
// grid (chunks, 16), 256 threads. Each block reduces rows_per_chunk rows of
// K[b]:[N,64] x V[b]:[N,64] into a 64x64 partial written to ws.
__global__ __launch_bounds__(256) void p1_partial(
    const float* __restrict__ K, const float* __restrict__ V,
    float* __restrict__ part, int rows_per_chunk)
{
    const int c = blockIdx.x;
    const int b = blockIdx.y;
    const int t = threadIdx.x;
    const int n0 = c * rows_per_chunk;

    const float* Kb = K + ((size_t)b * N_ + n0) * DK_;
    const float* Vb = V + ((size_t)b * N_ + n0) * DV_;

    __shared__ float sK[64 * 64];   // 16 KiB
    __shared__ float sV[64 * 64];   // 16 KiB

    const int kk4 = (t >> 4) * 4;   // 16 groups * 4 = 64 kk
    const int vv4 = (t & 15) * 4;   // 16 groups * 4 = 64 vv

    float acc[4][4] = {};

    for (int s = 0; s < rows_per_chunk; s += 64) {
        const float4* Ks = (const float4*)(Kb + (size_t)s * DK_);
        const float4* Vs = (const float4*)(Vb + (size_t)s * DV_);
        float4* sK4 = (float4*)sK;
        float4* sV4 = (float4*)sV;
        __syncthreads();            // protect previous subtile reads
        #pragma unroll
        for (int i = t; i < 1024; i += 256) {
            sK4[i] = Ks[i];
            sV4[i] = Vs[i];
        }
        __syncthreads();

        #pragma unroll 8
        for (int n = 0; n < 64; ++n) {
            const float4 fk = *(const float4*)&sK[n * 64 + kk4];
            const float4 fv = *(const float4*)&sV[n * 64 + vv4];
            acc[0][0] += fk.x * fv.x; acc[0][1] += fk.x * fv.y;
            acc[0][2] += fk.x * fv.z; acc[0][3] += fk.x * fv.w;
            acc[1][0] += fk.y * fv.x; acc[1][1] += fk.y * fv.y;
            acc[1][2] += fk.y * fv.z; acc[1][3] += fk.y * fv.w;
            acc[2][0] += fk.z * fv.x; acc[2][1] += fk.z * fv.y;
            acc[2][2] += fk.z * fv.z; acc[2][3] += fk.z * fv.w;
            acc[3][0] += fk.w * fv.x; acc[3][1] += fk.w * fv.y;
            acc[3][2] += fk.w * fv.z; acc[3][3] += fk.w * fv.w;
        }
    }

    float* P = part + ((size_t)c * B_ + b) * 4096;
    #pragma unroll
    for (int i = 0; i < 4; ++i) {
        *(float4*)&P[(kk4 + i) * 64 + vv4] =
            make_float4(acc[i][0], acc[i][1], acc[i][2], acc[i][3]);
    }
}

// ---------------- Phase 1b: reduce partials -> ktv ----------------
// grid 64 blocks x 256 threads; 16384 float4 outputs (16*64*64 floats).
__global__ __launch_bounds__(256) void p1_reduce(
    const float* __restrict__ part, float* __restrict__ ktv, int chunks)
{
    const int i = blockIdx.x * 256 + threadIdx.x;   // float4 index, < 16384
    float4 s = make_float4(0.f, 0.f, 0.f, 0.f);
    for (int c = 0; c < chunks; ++c) {
        const float4 p = ((const float4*)part)[(size_t)c * 16384 + i];
        s.x += p.x; s.y += p.y; s.z += p.z; s.w += p.w;
    }
    ((float4*)ktv)[i] = s;
}

// ---------------- Phase 2: out = q^T ktv ----------------
// grid (64, 16), 256 threads. Block tile: 128 n x 64 v. Thread tile: 8n x 4v.
__global__ __launch_bounds__(256) void p2(
    const float* __restrict__ q, const float* __restrict__ ktv,
    float* __restrict__ out)
{
    const int nb = blockIdx.x;       // 64 tiles of 128 n
    const int b  = blockIdx.y;
    const int t  = threadIdx.x;
    const int n0 = nb * 128;

    __shared__ float qs[64 * 128];   // 32 KiB: [k][n_local]
    __shared__ float ks[64 * 64];    // 16 KiB: [k][v]

    // stage ktv (4096 floats)
    const float4* kt4 = (const float4*)(ktv + (size_t)b * 4096);
    #pragma unroll
    for (int i = t; i < 1024; i += 256) ((float4*)ks)[i] = kt4[i];

    // stage q tile: 64 k-rows x 128 n (2048 float4), coalesced per row
    const float* qb = q + (size_t)b * DK_ * N_ + n0;
    #pragma unroll
    for (int i = t; i < 2048; i += 256) {
        const int k  = i >> 5;       // 32 float4 per row
        const int c4 = i & 31;
        ((float4*)&qs[k * 128])[c4] = *(const float4*)&qb[(size_t)k * N_ + c4 * 4];
    }
    __syncthreads();

    const int nl = (t >> 4) * 8;     // 16 groups * 8 = 128 n
    const int vl = (t & 15) * 4;     // 16 groups * 4 = 64 v

    float acc[8][4] = {};

    #pragma unroll 4
    for (int k = 0; k < 64; ++k) {
        const float4 kv = *(const float4*)&ks[k * 64 + vl];
        float qn[8];
        *(float4*)&qn[0] = *(const float4*)&qs[k * 128 + nl];
        *(float4*)&qn[4] = *(const float4*)&qs[k * 128 + nl + 4];
        #pragma unroll
        for (int i = 0; i < 8; ++i) {
            acc[i][0] += qn[i] * kv.x;
            acc[i][1] += qn[i] * kv.y;
            acc[i][2] += qn[i] * kv.z;
            acc[i][3] += qn[i] * kv.w;
        }
    }

    float* ob = out + ((size_t)b * N_ + n0 + nl) * DV_ + vl;
    #pragma unroll
    for (int i = 0; i < 8; ++i) {
        *(float4*)&ob[(size_t)i * DV_] =
            make_float4(acc[i][0], acc[i][1], acc[i][2], acc[i][3]);
    }
}

extern "C" void kernel_launch(void* const* d_in, const int* in_sizes, int n_in,
                              void* d_out, int out_size, void* d_ws, size_t ws_size,
                              hipStream_t stream)
{
    const float* q = (const float*)d_in[0];   // [16, 64, 8192]
    const float* k = (const float*)d_in[1];   // [16, 8192, 64]
    const float* v = (const float*)d_in[2];   // [16, 8192, 64]
    float* out = (float*)d_out;               // [16, 8192, 64]

    // ws layout: [chunks][16][4096] partials, then [16][4096] ktv.
    int chunks = 32;
    while (chunks > 1 &&
           (size_t)(chunks + 1) * B_ * 4096 * sizeof(float) > ws_size)
        chunks >>= 1;
    const int rows_per_chunk = N_ / chunks;   // multiple of 64 for all choices

    float* part = (float*)d_ws;
    float* ktv  = part + (size_t)chunks * B_ * 4096;

    p1_partial<<<dim3(chunks, B_), 256, 0, stream>>>(k, v, part, rows_per_chunk);
    p1_reduce<<<dim3(64), 256, 0, stream>>>(part, ktv, chunks);
    p2<<<dim3(64, B_), 256, 0, stream>>>(q, ktv, out);
}